// Round 8
// baseline (780.203 us; speedup 1.0000x reference)
//
#include <hip/hip_runtime.h>
#include <stdint.h>

#define NB 4096      // batch
#define NK 64        // neighbors
#define ND 128       // dim
#define NH 4         // heads
#define ES 136       // bf16 LDS row stride (ushorts): 272B, 16B-aligned rows
#define ESW (ES/2)   // 68 dwords per row
#define FS 130       // f32 stride for small kernels
#define MR 4         // row tile for mlp/final kernels

typedef __attribute__((ext_vector_type(8))) short bf16x8;
typedef __attribute__((ext_vector_type(4))) float f32x4;

__device__ __forceinline__ float seluf(float x) {
    float e = 1.6732632423543772f * (__expf(x) - 1.f);
    return 1.0507009873554805f * (x > 0.f ? x : e);
}
__device__ __forceinline__ float sigmoidf_(float x) {
    return __fdividef(1.f, 1.f + __expf(-x));
}
__device__ __forceinline__ uint32_t f2bf2(float a, float b) {
    uint32_t ua = __float_as_uint(a); ua += 0x7fffu + ((ua >> 16) & 1u);
    uint32_t ub = __float_as_uint(b); ub += 0x7fffu + ((ub >> 16) & 1u);
    return (ua >> 16) | (ub & 0xffff0000u);
}
__device__ __forceinline__ uint16_t bf1(float v) {
    uint32_t u = __float_as_uint(v); u += 0x7fffu + ((u >> 16) & 1u);
    return (uint16_t)(u >> 16);
}
__device__ __forceinline__ float bflo(uint32_t v) { return __uint_as_float(v << 16); }
__device__ __forceinline__ float bfhi(uint32_t v) { return __uint_as_float(v & 0xffff0000u); }

// ------------------------------------------------- prep: transpose weights to bf16 K-major
// wt1[h][n][k] = att1_w[h][k][n]  (k<128)   wt2[h][c][d] = att2_w[h][d][c]
// 64 blocks: h = bx>>4, sixteenth q = bx&15
__global__ __launch_bounds__(256)
void k_prep(const float* __restrict__ att1_w, const float* __restrict__ att2_w,
            uint16_t* __restrict__ wt1, uint16_t* __restrict__ wt2)
{
    const int h = blockIdx.x >> 4;
    const int q = blockIdx.x & 15;
    const int t = threadIdx.x;
    {
        int n = t >> 1, kh = t & 1;
        for (int k0 = q * 4; k0 < q * 4 + 4; ++k0) {
            int k = k0 * 2 + kh;
            float v = att1_w[(size_t)h * 32768 + (size_t)k * ND + n];
            float vo = __shfl_xor(v, 1, 64);
            if (kh == 0)
                ((uint32_t*)wt1)[((size_t)h * ND + n) * 64 + k0] = f2bf2(v, vo);
        }
    }
    {
        int c = t & 31, dh = t >> 5;
        int d0 = q;
        int d = d0 * 8 + dh;
        float v = att2_w[(size_t)h * 4096 + (size_t)d * 32 + c];
        float vo = __shfl_xor(v, 32, 64);
        if ((dh & 1) == 0)
            ((uint32_t*)wt2)[((size_t)h * 32 + c) * 64 + d0 * 4 + (dh >> 1)] = f2bf2(v, vo);
    }
}

// ---------------------------------------------------------------- kernel 1
__global__ __launch_bounds__(256, 4)
void k_att(const int* __restrict__ nodes, const int* __restrict__ neighbors,
           const float* __restrict__ u2e,
           const float* __restrict__ att1_w, const float* __restrict__ att1_b,
           const float* __restrict__ att2_b,
           const float* __restrict__ att3_w, const float* __restrict__ att3_b,
           const float* __restrict__ lin1_w, const float* __restrict__ lin1_b,
           const uint16_t* __restrict__ wt1, const uint16_t* __restrict__ wt2,
           float* __restrict__ hist_out,
           float* __restrict__ sums, float* __restrict__ sumsq)
{
    __shared__ alignas(16) uint16_t e_sh[NK * ES];   // normalized neighbor embeds, bf16
    __shared__ alignas(16) uint16_t s1_sh[NK * ES];  // att1 out; 4 wave-private 16-row regions
    __shared__ float u_sh[ND], up_sh[ND], hist_sh[ND];
    __shared__ float alpha_sh[NH * NK];              // all heads precomputed
    __shared__ float sc_sh[NK], att_sh[NK];
    __shared__ float red_sh[512];

    const int b = blockIdx.x;
    const int t = threadIdx.x;
    const int lane = t & 63;
    const int wave = t >> 6;
    const int lh = lane & 15;   // fragment row/col-in-tile
    const int lg = lane >> 4;   // k-group

    // ---- gather neighbors + l2norm into LDS (bf16) ----
    for (int k = wave; k < NK; k += 4) {
        int idx = neighbors[b * NK + k];
        float2 v = ((const float2*)(u2e + (size_t)idx * ND))[lane];
        float ss = v.x * v.x + v.y * v.y;
        #pragma unroll
        for (int m = 1; m < 64; m <<= 1) ss += __shfl_xor(ss, m, 64);
        float r = 1.0f / fmaxf(sqrtf(ss), 1e-12f);
        ((uint32_t*)e_sh)[k * ESW + lane] = f2bf2(v.x * r, v.y * r);
    }
    if (t < ND) {
        u_sh[t] = u2e[(size_t)nodes[b] * ND + t];
        hist_sh[t] = 0.f;
    }
    __syncthreads();

    // ---- alpha for ALL heads (wave h computes head h) ----
    {
        const float* lw = lin1_w + wave * ND;
        float lb = lin1_b[wave];
        #pragma unroll
        for (int it = 0; it < 4; ++it) {
            int k = it * 16 + (lane >> 2);
            int qd = lane & 3;
            const uint32_t* er = (const uint32_t*)e_sh + k * ESW + qd * 16;
            const float* lr = lw + qd * 32;
            float ap = 0.f;
            #pragma unroll 8
            for (int j2 = 0; j2 < 16; ++j2) {
                uint32_t v = er[j2];
                ap += bflo(v) * lr[2 * j2] + bfhi(v) * lr[2 * j2 + 1];
            }
            ap += __shfl_xor(ap, 1, 64);
            ap += __shfl_xor(ap, 2, 64);
            if (qd == 0)
                alpha_sh[wave * NK + k] = sigmoidf_(ap + lb) + 1.0f;
        }
    }
    // alpha consumed after barrier C of head 0 — ordering safe.

    for (int h = 0; h < NH; ++h) {
        // ---- per-wave rnorm of u (redundant across waves, register-only) ----
        float rnorm;
        {
            float a = u_sh[lane], c = u_sh[lane + 64];
            float ss = a * a + c * c;
            #pragma unroll
            for (int m = 1; m < 64; m <<= 1) ss += __shfl_xor(ss, m, 64);
            rnorm = 1.0f / fmaxf(sqrtf(ss), 1e-12f);
        }
        // ---- uproj partials (rank-1 half of att1) ----
        {
            int d = t & 127, half = t >> 7;
            const float* wb = att1_w + (size_t)h * 32768 + (size_t)(ND + half * 64) * ND + d;
            float p = 0.f;
            #pragma unroll 8
            for (int j = 0; j < 64; ++j)
                p += u_sh[half * 64 + j] * wb[j * ND];
            red_sh[t] = p * rnorm;
        }
        __syncthreads();                                   // A
        if (t < ND)
            up_sh[t] = red_sh[t] + red_sh[t + 128] + att1_b[h * ND + t];
        __syncthreads();                                   // B

        // ---- att1 via MFMA: wave w computes rows [16w,16w+16) x all 128 cols ----
        uint16_t* s1w = s1_sh + wave * 16 * ES;
        {
            const uint16_t* WB = wt1 + (size_t)h * ND * ND;
            f32x4 z = {0.f, 0.f, 0.f, 0.f};
            f32x4 acc[8] = {z, z, z, z, z, z, z, z};
            #pragma unroll
            for (int kk = 0; kk < 4; ++kk) {
                bf16x8 A = *(const bf16x8*)(e_sh + (wave * 16 + lh) * ES + kk * 32 + lg * 8);
                #pragma unroll
                for (int nt = 0; nt < 8; ++nt) {
                    bf16x8 Bf = *(const bf16x8*)(WB + (size_t)(nt * 16 + lh) * ND + kk * 32 + lg * 8);
                    acc[nt] = __builtin_amdgcn_mfma_f32_16x16x32_bf16(A, Bf, acc[nt], 0, 0, 0);
                }
            }
            #pragma unroll
            for (int nt = 0; nt < 8; ++nt) {
                float upv = up_sh[nt * 16 + lh];
                #pragma unroll
                for (int r = 0; r < 4; ++r) {
                    float v = seluf(acc[nt][r] + upv);
                    s1w[(lg * 4 + r) * ES + nt * 16 + lh] = bf1(v);
                }
            }
        }
        // ---- att2 via MFMA on wave-local s1 (no barrier; lgkmcnt only) ----
        {
            const uint16_t* WB2 = wt2 + (size_t)h * 32 * ND;
            f32x4 z = {0.f, 0.f, 0.f, 0.f};
            f32x4 acc2[2] = {z, z};
            #pragma unroll
            for (int kk = 0; kk < 4; ++kk) {
                bf16x8 A = *(const bf16x8*)(s1w + lh * ES + kk * 32 + lg * 8);
                #pragma unroll
                for (int nt = 0; nt < 2; ++nt) {
                    bf16x8 Bf = *(const bf16x8*)(WB2 + (size_t)(nt * 16 + lh) * ND + kk * 32 + lg * 8);
                    acc2[nt] = __builtin_amdgcn_mfma_f32_16x16x32_bf16(A, Bf, acc2[nt], 0, 0, 0);
                }
            }
            float w3a = att3_w[h * 32 + lh],      b2a = att2_b[h * 32 + lh];
            float w3b = att3_w[h * 32 + 16 + lh], b2b = att2_b[h * 32 + 16 + lh];
            float b3 = att3_b[h];
            #pragma unroll
            for (int r = 0; r < 4; ++r) {
                float v = seluf(acc2[0][r] + b2a) * w3a + seluf(acc2[1][r] + b2b) * w3b;
                v += __shfl_xor(v, 1, 64);
                v += __shfl_xor(v, 2, 64);
                v += __shfl_xor(v, 4, 64);
                v += __shfl_xor(v, 8, 64);
                if (lh == 0)
                    sc_sh[wave * 16 + lg * 4 + r] = v + b3;
            }
        }
        __syncthreads();                                   // C

        // ---- entmax: Newton on f(tau)=sum max(xs-tau,0)^q - 1 ----
        if (wave == 0) {
            float x   = sc_sh[lane];
            float am1 = alpha_sh[h * NK + lane] - 1.0f;
            float q   = 1.0f / am1;
            float em1 = q - 1.0f;
            float xs  = x * am1;
            float mx = xs;
            #pragma unroll
            for (int m = 1; m < 64; m <<= 1) mx = fmaxf(mx, __shfl_xor(mx, m, 64));
            float tau = mx - 1.0f;
            for (int it = 0; it < 6; ++it) {
                float tt = xs - tau;
                bool pos = tt > 0.f;
                float lgn = __logf(pos ? tt : 1.f);
                float p  = pos ? __expf(q * lgn) : 0.f;
                float dp = pos ? q * __expf(em1 * lgn) : 0.f;
                float s0 = p, s1 = dp;
                #pragma unroll
                for (int m = 1; m < 64; m <<= 1) {
                    s0 += __shfl_xor(s0, m, 64);
                    s1 += __shfl_xor(s1, m, 64);
                }
                tau += __fdividef(s0 - 1.0f, fmaxf(s1, 1e-30f));
                tau = fminf(tau, mx - 1e-6f);
            }
            float tt = xs - tau;
            bool pos = tt > 0.f;
            float p = pos ? __expf(q * __logf(pos ? tt : 1.f)) : 0.f;
            float s0 = p;
            #pragma unroll
            for (int m = 1; m < 64; m <<= 1) s0 += __shfl_xor(s0, m, 64);
            att_sh[lane] = __fdividef(p, s0);
        }
        __syncthreads();                                   // D

        // ---- pool: u[d] = sum_k e_n[k][d] * att[k] (dword-wise) ----
        {
            int d2 = t & 63, qk = t >> 6;
            const uint32_t* E = (const uint32_t*)e_sh;
            float px = 0.f, py = 0.f;
            #pragma unroll 8
            for (int k = qk * 16; k < qk * 16 + 16; ++k) {
                uint32_t v = E[k * ESW + d2];
                float a = att_sh[k];
                px += bflo(v) * a;
                py += bfhi(v) * a;
            }
            red_sh[qk * 128 + d2 * 2]     = px;
            red_sh[qk * 128 + d2 * 2 + 1] = py;
        }
        __syncthreads();                                   // E
        if (t < ND) {
            float un = red_sh[t] + red_sh[128 + t] + red_sh[256 + t] + red_sh[384 + t];
            u_sh[t] = un;
            hist_sh[t] += un;
        }
        __syncthreads();                                   // F
    }
    if (t < ND) {
        float hv = hist_sh[t] * 0.25f;
        hist_out[(size_t)b * ND + t] = hv;
        atomicAdd(&sums[t], hv);
        atomicAdd(&sumsq[t], hv * hv);
    }
}

// ---------------------------------------------------------------- h1 = selu(bn(hist) @ in_w + in_b), fused h1 stats
// grid NB/MR = 1024, 2 cols/thread
__global__ __launch_bounds__(256)
void k_mlp1(const float* __restrict__ hist,
            const float* __restrict__ sums, const float* __restrict__ sumsq,
            const float* __restrict__ bn_g, const float* __restrict__ bn_b,
            const float* __restrict__ in_w, const float* __restrict__ in_b,
            float* __restrict__ h1out,
            float* __restrict__ sums1, float* __restrict__ sumsq1)
{
    __shared__ float xh[MR * FS];
    int t = threadIdx.x;
    int row0 = blockIdx.x * MR;
    for (int i = t; i < MR * ND; i += 256) {
        int r = i >> 7, d = i & 127;
        float m  = sums[d]  * (1.f / 4096.f);
        float vv = sumsq[d] * (1.f / 4096.f) - m * m;
        float sc = bn_g[d] * rsqrtf(vv + 1e-5f);
        float sh = bn_b[d] - m * sc;
        xh[r * FS + d] = hist[(size_t)(row0 + r) * ND + d] * sc + sh;
    }
    __syncthreads();
    int dg = t & 63, rg = t >> 6;
    int d0 = dg * 2;
    float a0 = 0.f, a1 = 0.f;
    #pragma unroll 4
    for (int j = 0; j < ND; ++j) {
        float2 w = *(const float2*)(in_w + (size_t)j * ND + d0);
        float e = xh[rg * FS + j];
        a0 += e * w.x; a1 += e * w.y;
    }
    float h0 = seluf(a0 + in_b[d0]);
    float h1v = seluf(a1 + in_b[d0 + 1]);
    h1out[(size_t)(row0 + rg) * ND + d0]     = h0;
    h1out[(size_t)(row0 + rg) * ND + d0 + 1] = h1v;
    __syncthreads();
    xh[rg * FS + d0] = h0;
    xh[rg * FS + d0 + 1] = h1v;
    __syncthreads();
    if (t < ND) {
        float s = 0.f, q = 0.f;
        #pragma unroll
        for (int r = 0; r < MR; ++r) {
            float v = xh[r * FS + t];
            s += v; q += v * v;
        }
        atomicAdd(&sums1[t], s);
        atomicAdd(&sumsq1[t], q);
    }
}

// ---------------------------------------------------------------- final: neigh = bn1(h1)@out_w+b; gated combine
// grid NB/MR = 1024, 2 cols/thread
__global__ __launch_bounds__(256)
void k_final(const float* __restrict__ h1,
             const float* __restrict__ sums1, const float* __restrict__ sumsq1,
             const float* __restrict__ bn1_g, const float* __restrict__ bn1_b,
             const float* __restrict__ out_w, const float* __restrict__ out_b,
             const float* __restrict__ gate_w, const float* __restrict__ gate_b,
             const int* __restrict__ nodes, const float* __restrict__ u2e,
             float* __restrict__ out)
{
    __shared__ float xh[MR * FS];
    __shared__ float sf[MR * FS];
    __shared__ float ng[MR * FS];
    int t = threadIdx.x;
    int row0 = blockIdx.x * MR;
    for (int i = t; i < MR * ND; i += 256) {
        int r = i >> 7, d = i & 127;
        float m  = sums1[d]  * (1.f / 4096.f);
        float vv = sumsq1[d] * (1.f / 4096.f) - m * m;
        float sc = bn1_g[d] * rsqrtf(vv + 1e-5f);
        float sh = bn1_b[d] - m * sc;
        xh[r * FS + d] = h1[(size_t)(row0 + r) * ND + d] * sc + sh;
        sf[r * FS + d] = u2e[(size_t)nodes[row0 + r] * ND + d];
    }
    __syncthreads();
    int dg = t & 63, rg = t >> 6;
    int d0 = dg * 2;
    {
        float a0 = 0.f, a1 = 0.f;
        #pragma unroll 4
        for (int j = 0; j < ND; ++j) {
            float2 w = *(const float2*)(out_w + (size_t)j * ND + d0);
            float e = xh[rg * FS + j];
            a0 += e * w.x; a1 += e * w.y;
        }
        ng[rg * FS + d0]     = a0 + out_b[d0];
        ng[rg * FS + d0 + 1] = a1 + out_b[d0 + 1];
    }
    __syncthreads();
    {
        float a0 = 0.f, a1 = 0.f;
        #pragma unroll 2
        for (int j = 0; j < ND; ++j) {
            float2 w0 = *(const float2*)(gate_w + (size_t)j * ND + d0);
            float2 w1 = *(const float2*)(gate_w + (size_t)(ND + j) * ND + d0);
            float2 w2 = *(const float2*)(gate_w + (size_t)(2 * ND + j) * ND + d0);
            float s = sf[rg * FS + j];
            float n = ng[rg * FS + j];
            float p = s * n;
            a0 += s * w0.x + n * w1.x + p * w2.x;
            a1 += s * w0.y + n * w1.y + p * w2.y;
        }
        #pragma unroll
        for (int c = 0; c < 2; ++c) {
            int d = d0 + c;
            float acc = c ? a1 : a0;
            float gama = sigmoidf_(acc + gate_b[d]);
            float s = sf[rg * FS + d];
            float n = ng[rg * FS + d];
            out[(size_t)(row0 + rg) * ND + d] = gama * s + (1.f - gama) * n;
        }
    }
}

// ---------------------------------------------------------------- launch
extern "C" void kernel_launch(void* const* d_in, const int* in_sizes, int n_in,
                              void* d_out, int out_size, void* d_ws, size_t ws_size,
                              hipStream_t stream)
{
    const int*   nodes     = (const int*)d_in[0];
    const int*   neighbors = (const int*)d_in[1];
    const float* u2e       = (const float*)d_in[2];
    const float* att1_w    = (const float*)d_in[3];
    const float* att1_b    = (const float*)d_in[4];
    const float* att2_w    = (const float*)d_in[5];
    const float* att2_b    = (const float*)d_in[6];
    const float* att3_w    = (const float*)d_in[7];
    const float* att3_b    = (const float*)d_in[8];
    const float* lin1_w    = (const float*)d_in[9];
    const float* lin1_b    = (const float*)d_in[10];
    const float* gate_w    = (const float*)d_in[11];
    const float* gate_b    = (const float*)d_in[12];
    const float* bn_g      = (const float*)d_in[13];
    const float* bn_b      = (const float*)d_in[14];
    const float* bn1_g     = (const float*)d_in[15];
    const float* bn1_b     = (const float*)d_in[16];
    const float* in_w      = (const float*)d_in[17];
    const float* in_b      = (const float*)d_in[18];
    const float* out_w     = (const float*)d_in[19];
    const float* out_b     = (const float*)d_in[20];
    float* out = (float*)d_out;

    float* ws     = (float*)d_ws;
    float* g_hist = ws;                             // 4096*128 f32
    float* h1     = ws + (size_t)NB * ND;           // 4096*128 f32
    float* st     = ws + (size_t)2 * NB * ND;       // 512 f32 stats
    uint16_t* wt1 = (uint16_t*)(ws + (size_t)2 * NB * ND + 512);  // 4*128*128 bf16
    uint16_t* wt2 = wt1 + (size_t)NH * ND * ND;                   // 4*32*128 bf16

    (void)hipMemsetAsync(st, 0, 512 * sizeof(float), stream);

    k_prep<<<64, 256, 0, stream>>>(att1_w, att2_w, wt1, wt2);
    k_att<<<NB, 256, 0, stream>>>(nodes, neighbors, u2e,
                                  att1_w, att1_b, att2_b,
                                  att3_w, att3_b, lin1_w, lin1_b,
                                  wt1, wt2,
                                  g_hist, st, st + 128);
    k_mlp1<<<NB / MR, 256, 0, stream>>>(g_hist, st, st + 128, bn_g, bn_b,
                                        in_w, in_b, h1, st + 256, st + 384);
    k_final<<<NB / MR, 256, 0, stream>>>(h1, st + 256, st + 384, bn1_g, bn1_b,
                                         out_w, out_b, gate_w, gate_b,
                                         nodes, u2e, out);
}

// Round 9
// 526.042 us; speedup vs baseline: 1.4832x; 1.4832x over previous
//
#include <hip/hip_runtime.h>
#include <stdint.h>

#define NB 4096      // batch
#define NK 64        // neighbors
#define ND 128       // dim
#define NH 4         // heads
#define ES 136       // bf16 LDS row stride (ushorts): 272B, 16B-aligned rows
#define ESW (ES/2)   // 68 dwords per row
#define MR 16        // row tile for mlp/final kernels
#define GS 392       // gate tile row stride (ushorts), 784B = 49*16
#define SFS 132      // sf fp32 row stride

typedef __attribute__((ext_vector_type(8))) short bf16x8;
typedef __attribute__((ext_vector_type(4))) float f32x4;

__device__ __forceinline__ float seluf(float x) {
    float e = 1.6732632423543772f * (__expf(x) - 1.f);
    return 1.0507009873554805f * (x > 0.f ? x : e);
}
__device__ __forceinline__ float sigmoidf_(float x) {
    return __fdividef(1.f, 1.f + __expf(-x));
}
__device__ __forceinline__ uint32_t f2bf2(float a, float b) {
    uint32_t ua = __float_as_uint(a); ua += 0x7fffu + ((ua >> 16) & 1u);
    uint32_t ub = __float_as_uint(b); ub += 0x7fffu + ((ub >> 16) & 1u);
    return (ua >> 16) | (ub & 0xffff0000u);
}
__device__ __forceinline__ uint16_t bf1(float v) {
    uint32_t u = __float_as_uint(v); u += 0x7fffu + ((u >> 16) & 1u);
    return (uint16_t)(u >> 16);
}
__device__ __forceinline__ float bflo(uint32_t v) { return __uint_as_float(v << 16); }
__device__ __forceinline__ float bfhi(uint32_t v) { return __uint_as_float(v & 0xffff0000u); }
__device__ __forceinline__ float bf2f(uint16_t h) { return __uint_as_float(((uint32_t)h) << 16); }

// ------------------------------------------------- prep: bf16 K-major weight transposes
// blocks 0..63: wt1[h][n][k]=att1_w[h][k][n], wt2[h][c][d]=att2_w[h][d][c]
// blocks 64..71: wt_in[n][k]=in_w[k][n]; 72..79: wt_out[n][k]=out_w[k][n];
// blocks 80..87: wt_gate[n][k]=gate_w[k][n] (k<384)
__global__ __launch_bounds__(256)
void k_prep(const float* __restrict__ att1_w, const float* __restrict__ att2_w,
            const float* __restrict__ in_w, const float* __restrict__ out_w,
            const float* __restrict__ gate_w,
            uint16_t* __restrict__ wt1, uint16_t* __restrict__ wt2,
            uint16_t* __restrict__ wt_in, uint16_t* __restrict__ wt_out,
            uint16_t* __restrict__ wt_gate)
{
    const int bx = blockIdx.x;
    const int t = threadIdx.x;
    if (bx < 64) {
        const int h = bx >> 4;
        const int q = bx & 15;
        {
            int n = t >> 1, kh = t & 1;
            for (int k0 = q * 4; k0 < q * 4 + 4; ++k0) {
                int k = k0 * 2 + kh;
                float v = att1_w[(size_t)h * 32768 + (size_t)k * ND + n];
                float vo = __shfl_xor(v, 1, 64);
                if (kh == 0)
                    ((uint32_t*)wt1)[((size_t)h * ND + n) * 64 + k0] = f2bf2(v, vo);
            }
        }
        {
            int c = t & 31, dh = t >> 5;
            int d0 = q;
            int d = d0 * 8 + dh;
            float v = att2_w[(size_t)h * 4096 + (size_t)d * 32 + c];
            float vo = __shfl_xor(v, 32, 64);
            if ((dh & 1) == 0)
                ((uint32_t*)wt2)[((size_t)h * 32 + c) * 64 + d0 * 4 + (dh >> 1)] = f2bf2(v, vo);
        }
    } else if (bx < 72) {
        int n0 = (bx - 64) * 16;
        for (int n = n0; n < n0 + 16; ++n)
            for (int k = t; k < ND; k += 256)
                wt_in[n * ND + k] = bf1(in_w[(size_t)k * ND + n]);
    } else if (bx < 80) {
        int n0 = (bx - 72) * 16;
        for (int n = n0; n < n0 + 16; ++n)
            for (int k = t; k < ND; k += 256)
                wt_out[n * ND + k] = bf1(out_w[(size_t)k * ND + n]);
    } else {
        int n0 = (bx - 80) * 16;
        for (int n = n0; n < n0 + 16; ++n)
            for (int k = t; k < 384; k += 256)
                wt_gate[n * 384 + k] = bf1(gate_w[(size_t)k * ND + n]);
    }
}

// ---------------------------------------------------------------- kernel 1
__global__ __launch_bounds__(256, 4)
void k_att(const int* __restrict__ nodes, const int* __restrict__ neighbors,
           const float* __restrict__ u2e,
           const float* __restrict__ att1_w, const float* __restrict__ att1_b,
           const float* __restrict__ att2_b,
           const float* __restrict__ att3_w, const float* __restrict__ att3_b,
           const float* __restrict__ lin1_w, const float* __restrict__ lin1_b,
           const uint16_t* __restrict__ wt1, const uint16_t* __restrict__ wt2,
           float* __restrict__ hist_out,
           float* __restrict__ sums, float* __restrict__ sumsq)
{
    __shared__ alignas(16) uint16_t e_sh[NK * ES];   // normalized neighbor embeds, bf16
    __shared__ alignas(16) uint16_t s1_sh[NK * ES];  // att1 output, bf16
    __shared__ float u_sh[ND], up_sh[ND], hist_sh[ND];
    __shared__ float alpha_sh[NH * NK];              // all heads precomputed
    __shared__ float sc_sh[NK], att_sh[NK];
    __shared__ float red_sh[512];

    const int b = blockIdx.x;
    const int t = threadIdx.x;
    const int lane = t & 63;
    const int wave = t >> 6;
    const int lh = lane & 15;   // fragment row/col-in-tile
    const int lg = lane >> 4;   // k-group

    // ---- gather neighbors + l2norm into LDS (bf16) ----
    for (int k = wave; k < NK; k += 4) {
        int idx = neighbors[b * NK + k];
        float2 v = ((const float2*)(u2e + (size_t)idx * ND))[lane];
        float ss = v.x * v.x + v.y * v.y;
        #pragma unroll
        for (int m = 1; m < 64; m <<= 1) ss += __shfl_xor(ss, m, 64);
        float r = 1.0f / fmaxf(sqrtf(ss), 1e-12f);
        ((uint32_t*)e_sh)[k * ESW + lane] = f2bf2(v.x * r, v.y * r);
    }
    if (t < ND) {
        u_sh[t] = u2e[(size_t)nodes[b] * ND + t];
        hist_sh[t] = 0.f;
    }
    __syncthreads();

    // ---- alpha for ALL heads (wave h computes head h); consumed after barrier C of head 0 ----
    {
        const float* lw = lin1_w + wave * ND;
        float lb = lin1_b[wave];
        #pragma unroll
        for (int it = 0; it < 4; ++it) {
            int k = it * 16 + (lane >> 2);
            int qd = lane & 3;
            const uint32_t* er = (const uint32_t*)e_sh + k * ESW + qd * 16;
            const float* lr = lw + qd * 32;
            float ap = 0.f;
            #pragma unroll 8
            for (int j2 = 0; j2 < 16; ++j2) {
                uint32_t v = er[j2];
                ap += bflo(v) * lr[2 * j2] + bfhi(v) * lr[2 * j2 + 1];
            }
            ap += __shfl_xor(ap, 1, 64);
            ap += __shfl_xor(ap, 2, 64);
            if (qd == 0)
                alpha_sh[wave * NK + k] = sigmoidf_(ap + lb) + 1.0f;
        }
    }

    for (int h = 0; h < NH; ++h) {
        // ---- per-wave rnorm of u (register-only) ----
        float rnorm;
        {
            float a = u_sh[lane], c = u_sh[lane + 64];
            float ss = a * a + c * c;
            #pragma unroll
            for (int m = 1; m < 64; m <<= 1) ss += __shfl_xor(ss, m, 64);
            rnorm = 1.0f / fmaxf(sqrtf(ss), 1e-12f);
        }
        // ---- uproj partials (rank-1 half of att1) ----
        {
            int d = t & 127, half = t >> 7;
            const float* wb = att1_w + (size_t)h * 32768 + (size_t)(ND + half * 64) * ND + d;
            float p = 0.f;
            #pragma unroll 8
            for (int j = 0; j < 64; ++j)
                p += u_sh[half * 64 + j] * wb[j * ND];
            red_sh[t] = p * rnorm;
        }
        __syncthreads();                                   // A
        if (t < ND)
            up_sh[t] = red_sh[t] + red_sh[t + 128] + att1_b[h * ND + t];
        __syncthreads();                                   // B

        // ---- att1 via MFMA (R5 mapping): wave owns cols [32w,32w+32); B in regs, reused x4 ----
        {
            const uint16_t* WB = wt1 + ((size_t)h * ND + wave * 32) * ND;
            bf16x8 B[4][2];
            #pragma unroll
            for (int kk = 0; kk < 4; ++kk)
                #pragma unroll
                for (int nt = 0; nt < 2; ++nt)
                    B[kk][nt] = *(const bf16x8*)(WB + (nt * 16 + lh) * ND + kk * 32 + lg * 8);
            f32x4 z = {0.f, 0.f, 0.f, 0.f};
            f32x4 acc[4][2] = {{z, z}, {z, z}, {z, z}, {z, z}};
            #pragma unroll
            for (int mt = 0; mt < 4; ++mt) {
                #pragma unroll
                for (int kk = 0; kk < 4; ++kk) {
                    bf16x8 A = *(const bf16x8*)(e_sh + (mt * 16 + lh) * ES + kk * 32 + lg * 8);
                    acc[mt][0] = __builtin_amdgcn_mfma_f32_16x16x32_bf16(A, B[kk][0], acc[mt][0], 0, 0, 0);
                    acc[mt][1] = __builtin_amdgcn_mfma_f32_16x16x32_bf16(A, B[kk][1], acc[mt][1], 0, 0, 0);
                }
            }
            float up0 = up_sh[wave * 32 + lh];
            float up1 = up_sh[wave * 32 + 16 + lh];
            #pragma unroll
            for (int mt = 0; mt < 4; ++mt)
                #pragma unroll
                for (int nt = 0; nt < 2; ++nt) {
                    float upv = nt ? up1 : up0;
                    #pragma unroll
                    for (int r = 0; r < 4; ++r) {
                        float v = seluf(acc[mt][nt][r] + upv);
                        s1_sh[(mt * 16 + lg * 4 + r) * ES + wave * 32 + nt * 16 + lh] = bf1(v);
                    }
                }
        }
        __syncthreads();                                   // C (att1 cols -> att2 rows)

        // ---- att2 via MFMA: wave owns rows [16w,16w+16); then selu+att3 dot ----
        {
            const uint16_t* WB2 = wt2 + (size_t)h * 32 * ND;
            bf16x8 B2[4][2];
            #pragma unroll
            for (int kk = 0; kk < 4; ++kk)
                #pragma unroll
                for (int nt = 0; nt < 2; ++nt)
                    B2[kk][nt] = *(const bf16x8*)(WB2 + (nt * 16 + lh) * ND + kk * 32 + lg * 8);
            f32x4 z = {0.f, 0.f, 0.f, 0.f};
            f32x4 acc2[2] = {z, z};
            #pragma unroll
            for (int kk = 0; kk < 4; ++kk) {
                bf16x8 A = *(const bf16x8*)(s1_sh + (wave * 16 + lh) * ES + kk * 32 + lg * 8);
                acc2[0] = __builtin_amdgcn_mfma_f32_16x16x32_bf16(A, B2[kk][0], acc2[0], 0, 0, 0);
                acc2[1] = __builtin_amdgcn_mfma_f32_16x16x32_bf16(A, B2[kk][1], acc2[1], 0, 0, 0);
            }
            float w3a = att3_w[h * 32 + lh],      b2a = att2_b[h * 32 + lh];
            float w3b = att3_w[h * 32 + 16 + lh], b2b = att2_b[h * 32 + 16 + lh];
            float b3 = att3_b[h];
            #pragma unroll
            for (int r = 0; r < 4; ++r) {
                float v = seluf(acc2[0][r] + b2a) * w3a + seluf(acc2[1][r] + b2b) * w3b;
                v += __shfl_xor(v, 1, 64);
                v += __shfl_xor(v, 2, 64);
                v += __shfl_xor(v, 4, 64);
                v += __shfl_xor(v, 8, 64);
                if (lh == 0)
                    sc_sh[wave * 16 + lg * 4 + r] = v + b3;
            }
        }
        __syncthreads();                                   // D

        // ---- entmax: Newton on f(tau)=sum max(xs-tau,0)^q - 1 ----
        if (wave == 0) {
            float x   = sc_sh[lane];
            float am1 = alpha_sh[h * NK + lane] - 1.0f;
            float q   = 1.0f / am1;
            float em1 = q - 1.0f;
            float xs  = x * am1;
            float mx = xs;
            #pragma unroll
            for (int m = 1; m < 64; m <<= 1) mx = fmaxf(mx, __shfl_xor(mx, m, 64));
            float tau = mx - 1.0f;
            for (int it = 0; it < 6; ++it) {
                float tt = xs - tau;
                bool pos = tt > 0.f;
                float lgn = __logf(pos ? tt : 1.f);
                float p  = pos ? __expf(q * lgn) : 0.f;
                float dp = pos ? q * __expf(em1 * lgn) : 0.f;
                float s0 = p, s1 = dp;
                #pragma unroll
                for (int m = 1; m < 64; m <<= 1) {
                    s0 += __shfl_xor(s0, m, 64);
                    s1 += __shfl_xor(s1, m, 64);
                }
                tau += __fdividef(s0 - 1.0f, fmaxf(s1, 1e-30f));
                tau = fminf(tau, mx - 1e-6f);
            }
            float tt = xs - tau;
            bool pos = tt > 0.f;
            float p = pos ? __expf(q * __logf(pos ? tt : 1.f)) : 0.f;
            float s0 = p;
            #pragma unroll
            for (int m = 1; m < 64; m <<= 1) s0 += __shfl_xor(s0, m, 64);
            att_sh[lane] = __fdividef(p, s0);
        }
        __syncthreads();                                   // E

        // ---- pool: u[d] = sum_k e_n[k][d] * att[k] (dword-wise) ----
        {
            int d2 = t & 63, qk = t >> 6;
            const uint32_t* E = (const uint32_t*)e_sh;
            float px = 0.f, py = 0.f;
            #pragma unroll 8
            for (int k = qk * 16; k < qk * 16 + 16; ++k) {
                uint32_t v = E[k * ESW + d2];
                float a = att_sh[k];
                px += bflo(v) * a;
                py += bfhi(v) * a;
            }
            red_sh[qk * 128 + d2 * 2]     = px;
            red_sh[qk * 128 + d2 * 2 + 1] = py;
        }
        __syncthreads();                                   // F
        if (t < ND) {
            float un = red_sh[t] + red_sh[128 + t] + red_sh[256 + t] + red_sh[384 + t];
            u_sh[t] = un;
            hist_sh[t] += un;
        }
        __syncthreads();                                   // G
    }
    if (t < ND) {
        float hv = hist_sh[t] * 0.25f;
        hist_out[(size_t)b * ND + t] = hv;
        atomicAdd(&sums[t], hv);
        atomicAdd(&sumsq[t], hv * hv);
    }
}

// ---------------------------------------------------------------- h1 = selu(bn(hist)@in_w+b) via MFMA, fused h1 stats
// grid 256, 16 rows/block; h1 stored bf16
__global__ __launch_bounds__(256)
void k_mlp1(const float* __restrict__ hist,
            const float* __restrict__ sums, const float* __restrict__ sumsq,
            const float* __restrict__ bn_g, const float* __restrict__ bn_b,
            const uint16_t* __restrict__ wt_in, const float* __restrict__ in_b,
            uint16_t* __restrict__ h1b,
            float* __restrict__ sums1, float* __restrict__ sumsq1)
{
    __shared__ alignas(16) uint16_t xh[MR * ES];
    const int t = threadIdx.x;
    const int lane = t & 63;
    const int wave = t >> 6;
    const int lh = lane & 15;
    const int lg = lane >> 4;
    const int row0 = blockIdx.x * MR;

    // stage: bn(hist) -> bf16 tile
    #pragma unroll
    for (int it = 0; it < 4; ++it) {
        int pos = t + it * 256;          // 0..1023 dword positions
        int r = pos >> 6, d2 = pos & 63;
        int d0 = d2 * 2;
        float m0 = sums[d0] * (1.f / 4096.f);
        float v0 = sumsq[d0] * (1.f / 4096.f) - m0 * m0;
        float sc0 = bn_g[d0] * rsqrtf(v0 + 1e-5f);
        float sh0 = bn_b[d0] - m0 * sc0;
        float m1 = sums[d0 + 1] * (1.f / 4096.f);
        float v1 = sumsq[d0 + 1] * (1.f / 4096.f) - m1 * m1;
        float sc1 = bn_g[d0 + 1] * rsqrtf(v1 + 1e-5f);
        float sh1 = bn_b[d0 + 1] - m1 * sc1;
        float2 hv = *(const float2*)(hist + (size_t)(row0 + r) * ND + d0);
        ((uint32_t*)xh)[r * ESW + d2] = f2bf2(hv.x * sc0 + sh0, hv.y * sc1 + sh1);
    }
    __syncthreads();

    // MFMA: wave owns cols [32w,32w+32)
    const uint16_t* WB = wt_in + (size_t)(wave * 32) * ND;
    bf16x8 B[4][2];
    #pragma unroll
    for (int kk = 0; kk < 4; ++kk)
        #pragma unroll
        for (int nt = 0; nt < 2; ++nt)
            B[kk][nt] = *(const bf16x8*)(WB + (nt * 16 + lh) * ND + kk * 32 + lg * 8);
    f32x4 z = {0.f, 0.f, 0.f, 0.f};
    f32x4 acc[2] = {z, z};
    #pragma unroll
    for (int kk = 0; kk < 4; ++kk) {
        bf16x8 A = *(const bf16x8*)(xh + lh * ES + kk * 32 + lg * 8);
        acc[0] = __builtin_amdgcn_mfma_f32_16x16x32_bf16(A, B[kk][0], acc[0], 0, 0, 0);
        acc[1] = __builtin_amdgcn_mfma_f32_16x16x32_bf16(A, B[kk][1], acc[1], 0, 0, 0);
    }
    #pragma unroll
    for (int nt = 0; nt < 2; ++nt) {
        int col = wave * 32 + nt * 16 + lh;
        float bia = in_b[col];
        float s = 0.f, q = 0.f;
        #pragma unroll
        for (int r = 0; r < 4; ++r) {
            int row = lg * 4 + r;
            float hv = seluf(acc[nt][r] + bia);
            h1b[(size_t)(row0 + row) * ND + col] = bf1(hv);
            s += hv; q += hv * hv;
        }
        // reduce over lg (rows 0..15 of this block)
        s += __shfl_xor(s, 16, 64); s += __shfl_xor(s, 32, 64);
        q += __shfl_xor(q, 16, 64); q += __shfl_xor(q, 32, 64);
        if (lg == 0) {
            atomicAdd(&sums1[col], s);
            atomicAdd(&sumsq1[col], q);
        }
    }
}

// ---------------------------------------------------------------- final via MFMA: neigh + gated combine
// grid 256, 16 rows/block
__global__ __launch_bounds__(256)
void k_final(const uint16_t* __restrict__ h1b,
             const float* __restrict__ sums1, const float* __restrict__ sumsq1,
             const float* __restrict__ bn1_g, const float* __restrict__ bn1_b,
             const uint16_t* __restrict__ wt_out, const float* __restrict__ out_b,
             const uint16_t* __restrict__ wt_gate, const float* __restrict__ gate_b,
             const int* __restrict__ nodes, const float* __restrict__ u2e,
             float* __restrict__ out)
{
    __shared__ alignas(16) uint16_t xh[MR * ES];     // bn1(h1) bf16
    __shared__ float sff[MR * SFS];                  // self features fp32
    __shared__ alignas(16) uint16_t gtile[MR * GS];  // [sf | neigh | sf*neigh] bf16
    const int t = threadIdx.x;
    const int lane = t & 63;
    const int wave = t >> 6;
    const int lh = lane & 15;
    const int lg = lane >> 4;
    const int row0 = blockIdx.x * MR;

    // stage
    #pragma unroll
    for (int it = 0; it < 4; ++it) {
        int pos = t + it * 256;
        int r = pos >> 6, d2 = pos & 63;
        int d0 = d2 * 2;
        float m0 = sums1[d0] * (1.f / 4096.f);
        float v0 = sumsq1[d0] * (1.f / 4096.f) - m0 * m0;
        float sc0 = bn1_g[d0] * rsqrtf(v0 + 1e-5f);
        float sh0 = bn1_b[d0] - m0 * sc0;
        float m1 = sums1[d0 + 1] * (1.f / 4096.f);
        float v1 = sumsq1[d0 + 1] * (1.f / 4096.f) - m1 * m1;
        float sc1 = bn1_g[d0 + 1] * rsqrtf(v1 + 1e-5f);
        float sh1 = bn1_b[d0 + 1] - m1 * sc1;
        uint32_t hw = ((const uint32_t*)h1b)[(size_t)(row0 + r) * 64 + d2];
        ((uint32_t*)xh)[r * ESW + d2] = f2bf2(bflo(hw) * sc0 + sh0, bfhi(hw) * sc1 + sh1);
        float2 sv = *(const float2*)(u2e + (size_t)nodes[row0 + r] * ND + d0);
        sff[r * SFS + d0]     = sv.x;
        sff[r * SFS + d0 + 1] = sv.y;
        ((uint32_t*)gtile)[r * (GS / 2) + d2] = f2bf2(sv.x, sv.y);
    }
    __syncthreads();

    // neigh = xh @ wt_out (wave owns cols [32w,32w+32)); keep fragments in regs
    f32x4 z = {0.f, 0.f, 0.f, 0.f};
    f32x4 accN[2] = {z, z};
    {
        const uint16_t* WB = wt_out + (size_t)(wave * 32) * ND;
        bf16x8 B[4][2];
        #pragma unroll
        for (int kk = 0; kk < 4; ++kk)
            #pragma unroll
            for (int nt = 0; nt < 2; ++nt)
                B[kk][nt] = *(const bf16x8*)(WB + (nt * 16 + lh) * ND + kk * 32 + lg * 8);
        #pragma unroll
        for (int kk = 0; kk < 4; ++kk) {
            bf16x8 A = *(const bf16x8*)(xh + lh * ES + kk * 32 + lg * 8);
            accN[0] = __builtin_amdgcn_mfma_f32_16x16x32_bf16(A, B[kk][0], accN[0], 0, 0, 0);
            accN[1] = __builtin_amdgcn_mfma_f32_16x16x32_bf16(A, B[kk][1], accN[1], 0, 0, 0);
        }
    }
    // write neigh and sf*neigh slices of gtile
    #pragma unroll
    for (int nt = 0; nt < 2; ++nt) {
        int col = wave * 32 + nt * 16 + lh;
        float bia = out_b[col];
        #pragma unroll
        for (int r = 0; r < 4; ++r) {
            int row = lg * 4 + r;
            float n = accN[nt][r] + bia;
            float s = sff[row * SFS + col];
            gtile[row * GS + 128 + col] = bf1(n);
            gtile[row * GS + 256 + col] = bf1(s * n);
        }
    }
    __syncthreads();

    // gamma = sigmoid(gtile @ wt_gate + gate_b)
    f32x4 accG[2] = {z, z};
    #pragma unroll
    for (int kk = 0; kk < 12; ++kk) {
        bf16x8 A = *(const bf16x8*)(gtile + lh * GS + kk * 32 + lg * 8);
        #pragma unroll
        for (int nt = 0; nt < 2; ++nt) {
            bf16x8 Bf = *(const bf16x8*)(wt_gate + (size_t)(wave * 32 + nt * 16 + lh) * 384 + kk * 32 + lg * 8);
            accG[nt] = __builtin_amdgcn_mfma_f32_16x16x32_bf16(A, Bf, accG[nt], 0, 0, 0);
        }
    }
    #pragma unroll
    for (int nt = 0; nt < 2; ++nt) {
        int col = wave * 32 + nt * 16 + lh;
        float gb = gate_b[col];
        float ob = out_b[col];
        #pragma unroll
        for (int r = 0; r < 4; ++r) {
            int row = lg * 4 + r;
            float gama = sigmoidf_(accG[nt][r] + gb);
            float s = sff[row * SFS + col];
            float n = accN[nt][r] + ob;
            out[(size_t)(row0 + row) * ND + col] = gama * s + (1.f - gama) * n;
        }
    }
}

// ---------------------------------------------------------------- launch
extern "C" void kernel_launch(void* const* d_in, const int* in_sizes, int n_in,
                              void* d_out, int out_size, void* d_ws, size_t ws_size,
                              hipStream_t stream)
{
    const int*   nodes     = (const int*)d_in[0];
    const int*   neighbors = (const int*)d_in[1];
    const float* u2e       = (const float*)d_in[2];
    const float* att1_w    = (const float*)d_in[3];
    const float* att1_b    = (const float*)d_in[4];
    const float* att2_w    = (const float*)d_in[5];
    const float* att2_b    = (const float*)d_in[6];
    const float* att3_w    = (const float*)d_in[7];
    const float* att3_b    = (const float*)d_in[8];
    const float* lin1_w    = (const float*)d_in[9];
    const float* lin1_b    = (const float*)d_in[10];
    const float* gate_w    = (const float*)d_in[11];
    const float* gate_b    = (const float*)d_in[12];
    const float* bn_g      = (const float*)d_in[13];
    const float* bn_b      = (const float*)d_in[14];
    const float* bn1_g     = (const float*)d_in[15];
    const float* bn1_b     = (const float*)d_in[16];
    const float* in_w      = (const float*)d_in[17];
    const float* in_b      = (const float*)d_in[18];
    const float* out_w     = (const float*)d_in[19];
    const float* out_b     = (const float*)d_in[20];
    float* out = (float*)d_out;

    float* ws      = (float*)d_ws;
    float* g_hist  = ws;                                   // 4096*128 f32
    float* st      = ws + (size_t)NB * ND;                 // 512 f32 stats
    uint16_t* wt1  = (uint16_t*)(st + 512);                // 4*128*128 bf16
    uint16_t* wt2  = wt1 + (size_t)NH * ND * ND;           // 4*32*128
    uint16_t* wt_in   = wt2 + (size_t)NH * 32 * ND;        // 128*128
    uint16_t* wt_out  = wt_in + (size_t)ND * ND;           // 128*128
    uint16_t* wt_gate = wt_out + (size_t)ND * ND;          // 128*384
    uint16_t* h1b     = wt_gate + (size_t)ND * 384;        // 4096*128 bf16

    (void)hipMemsetAsync(st, 0, 512 * sizeof(float), stream);

    k_prep<<<88, 256, 0, stream>>>(att1_w, att2_w, in_w, out_w, gate_w,
                                   wt1, wt2, wt_in, wt_out, wt_gate);
    k_att<<<NB, 256, 0, stream>>>(nodes, neighbors, u2e,
                                  att1_w, att1_b, att2_b,
                                  att3_w, att3_b, lin1_w, lin1_b,
                                  wt1, wt2,
                                  g_hist, st, st + 128);
    k_mlp1<<<NB / MR, 256, 0, stream>>>(g_hist, st, st + 128, bn_g, bn_b,
                                        wt_in, in_b, h1b, st + 256, st + 384);
    k_final<<<NB / MR, 256, 0, stream>>>(h1b, st + 256, st + 384, bn1_g, bn1_b,
                                         wt_out, out_b, wt_gate, gate_b,
                                         nodes, u2e, out);
}